// Round 3
// baseline (102.770 us; speedup 1.0000x reference)
//
#include <hip/hip_runtime.h>
#include <hip/hip_bf16.h>

// ContrastiveLoss: B=4096 rows, D=128 feature dim, C=100 classes.
// loss = -(1/B^2) * sum_k S_k * w_{l_k},  w_c = count_c/(count_c+1e-12)
//   S_k  = sum_j logits[k,j] - B*m_k - B*log(Z_k + 1e-12)
//   logits[k,j] = w_k . a_j,  w_k = (a_k + (a_k @ Cov[l_k]) / (2 T^2)) / T
// 5 dispatches: bucket (PARALLEL label sort + chunk table), prep
// (class-grouped: 16 rows share ONE Cov[c] stream -> 268MB -> ~17MB L2
// traffic), main (MFMA flash logits), combine (S_k per row, 4 rows/block),
// final (weighted sum from bucket's histogram).
// LESSONS: (R4) heavy fp64 tails fused into the MFMA kernel wreck regalloc.
// (R7) single-address global tickets at 4096-block scale serialize ~145us.
// (R8) bucket with a SERIAL t==0 chunk loop cost ~10-15us (whole GPU idle
// behind ~770 dependent stores) -> regressed +25us. This version's bucket
// is fully parallel: LDS histogram + wave-0 shuffle scans + per-class
// chunk emission + atomic scatter. Chunked prep numerics were PROVEN
// bit-exact in R8 (absmax 0.0); perm order nondeterminism does not affect
// any output bit (each row's FMA chain reads only its own row + Cov).
// (R9=R2) combine coarsening 4096->1024 blocks: neutral -> dispatch/block
// overhead is not the bottleneck. Budget: ~19us kernels + ~82us harness
// poison fills (2 x 256MiB @ ~41us, untouchable).

#define DIM 128
#define TEMP 0.07f
#define NBIN 128      // label bins (C=100 fits)
#define CHUNK 16      // rows per prep block (single class per chunk)
#define MAXCHUNK 512  // >= 100 + B/CHUNK = 356 worst case

typedef __attribute__((ext_vector_type(8))) short short8;
typedef __attribute__((ext_vector_type(4))) float floatx4;

static __device__ __forceinline__ unsigned short f2bf(float f) {
    __hip_bfloat16 h = __float2bfloat16(f);
    union { __hip_bfloat16 h; unsigned short u; } c;
    c.h = h;
    return c.u;
}

// One block, FULLY PARALLEL (no serial t==0 section -- R8 lesson):
// 1) LDS-atomic histogram of labels.
// 2) Wave 0: exclusive prefix scans over the 128 bins (row offsets and
//    chunk offsets) via __shfl_up, 2 bins/lane.
// 3) Threads t<128 emit their class's chunk descriptors in parallel
//    (<= ceil(60/16) = 4 per class).
// 4) Atomic scatter of row ids into label-sorted perm.
// meta[0] = nchunks, meta[1..NBIN] = class counts (reused by final_kernel).
__global__ __launch_bounds__(1024) void bucket_kernel(
    const int* __restrict__ labels, int B, int* __restrict__ perm,
    int* __restrict__ ckCls, int* __restrict__ ckBase,
    int* __restrict__ ckNv, int* __restrict__ meta) {
    __shared__ int cnt[NBIN], coff[NBIN], ckoff[NBIN], pos[NBIN];
    const int t = threadIdx.x;
    if (t < NBIN) cnt[t] = 0;
    __syncthreads();
    for (int i = t; i < B; i += 1024) atomicAdd(&cnt[labels[i]], 1);
    __syncthreads();
    if (t < 64) {  // wave 0: 4 interleaved 64-wide scans (2 bins/lane)
        const int c0 = cnt[t], c1 = cnt[64 + t];
        const int n0 = (c0 + CHUNK - 1) / CHUNK;
        const int n1 = (c1 + CHUNK - 1) / CHUNK;
        int a0 = c0, a1 = c1, b0 = n0, b1 = n1;
#pragma unroll
        for (int o = 1; o < 64; o <<= 1) {
            int x;
            x = __shfl_up(a0, o); if (t >= o) a0 += x;
            x = __shfl_up(a1, o); if (t >= o) a1 += x;
            x = __shfl_up(b0, o); if (t >= o) b0 += x;
            x = __shfl_up(b1, o); if (t >= o) b1 += x;
        }
        const int tot0 = __shfl(a0, 63);
        const int totc0 = __shfl(b0, 63);
        coff[t] = a0 - c0;
        coff[64 + t] = tot0 + a1 - c1;
        ckoff[t] = b0 - n0;
        ckoff[64 + t] = totc0 + b1 - n1;
        if (t == 63) meta[0] = totc0 + b1;  // total chunk count
    }
    __syncthreads();
    if (t < NBIN) {
        pos[t] = coff[t];
        meta[1 + t] = cnt[t];
        const int n = cnt[t], base = coff[t], cb = ckoff[t];
        for (int j = 0, k = 0; j < n; j += CHUNK, ++k) {
            ckCls[cb + k] = t;
            ckBase[cb + k] = base + j;
            ckNv[cb + k] = (n - j < CHUNK) ? (n - j) : CHUNK;
        }
    }
    __syncthreads();
    for (int i = t; i < B; i += 1024) {
        const int p = atomicAdd(&pos[labels[i]], 1);
        perm[p] = i;
    }
}

// Class-grouped prep (numerics bit-exact-verified in R8). Block b handles
// chunk b: nv (<=16) rows of one class. Stage A rows transposed in LDS
// (a_t[d][k]); stream Cov[cls] ONCE (each thread owns column e, both
// halves' Cov loads dedup in L1), broadcast-read 8 A scalars per d from
// LDS, 8 parallel fp32 fmaf chains per thread. Chain order (d ascending)
// matches the per-row version bit-for-bit (fma operand order commutes).
__global__ __launch_bounds__(256) void prep_kernel(
    const float* __restrict__ A, const float* __restrict__ Cov,
    unsigned short* __restrict__ Wbf, unsigned short* __restrict__ Abf,
    const int* __restrict__ perm, const int* __restrict__ ckCls,
    const int* __restrict__ ckBase, const int* __restrict__ ckNv,
    const int* __restrict__ meta) {
    const float inv2t2 = 1.0f / (2.0f * TEMP * TEMP);
    const float invt = 1.0f / TEMP;
    __shared__ float a_t[DIM][CHUNK];  // 8 KB, a_t[d][k] = A[row_k][d]
    __shared__ int rowids[CHUNK];
    const int b = blockIdx.x;
    if (b >= meta[0]) return;
    const int cls = ckCls[b], base = ckBase[b], nv = ckNv[b];
    const int t = threadIdx.x;
    {
        const int k = t >> 4, j = t & 15;
        const int row = perm[base + (k < nv ? k : 0)];  // clamp padding
        if (j == 0) rowids[k] = row;
        const float4 v0 = *(const float4*)(A + (size_t)row * DIM + j * 8);
        const float4 v1 = *(const float4*)(A + (size_t)row * DIM + j * 8 + 4);
        const float va[8] = {v0.x, v0.y, v0.z, v0.w, v1.x, v1.y, v1.z, v1.w};
        short8 ab;
#pragma unroll
        for (int i = 0; i < 8; ++i) {
            a_t[j * 8 + i][k] = va[i];
            ab[i] = (short)f2bf(va[i]);
        }
        if (k < nv) *(short8*)(Abf + (size_t)row * DIM + j * 8) = ab;
    }
    __syncthreads();
    const int e = t & 127, half = t >> 7;  // half: rows 0-7 or 8-15
    const float* Cp = Cov + (size_t)cls * (DIM * DIM) + e;
    float acc[8] = {0.f, 0.f, 0.f, 0.f, 0.f, 0.f, 0.f, 0.f};
#pragma unroll 8
    for (int d = 0; d < DIM; ++d) {
        const float cov = Cp[(size_t)d * DIM];
        const float4 w0 = *(const float4*)&a_t[d][half * 8];
        const float4 w1 = *(const float4*)&a_t[d][half * 8 + 4];
        acc[0] = fmaf(w0.x, cov, acc[0]);
        acc[1] = fmaf(w0.y, cov, acc[1]);
        acc[2] = fmaf(w0.z, cov, acc[2]);
        acc[3] = fmaf(w0.w, cov, acc[3]);
        acc[4] = fmaf(w1.x, cov, acc[4]);
        acc[5] = fmaf(w1.y, cov, acc[5]);
        acc[6] = fmaf(w1.z, cov, acc[6]);
        acc[7] = fmaf(w1.w, cov, acc[7]);
    }
#pragma unroll
    for (int kk = 0; kk < 8; ++kk) {
        const int krow = half * 8 + kk;
        if (krow < nv) {
            const int row = rowids[krow];
            const float av = A[(size_t)row * DIM + e];
            Wbf[(size_t)row * DIM + e] = f2bf((av + acc[kk] * inv2t2) * invt);
        }
    }
}

// Block = 4 waves (2M x 2N). Block tile: 128 k-rows x 64 j-cols, K=128
// unrolled. Wave tile: 64x32 via 4(m) x 2(n) mfma_f32_16x16x32_bf16.
// LDS: PITCH=128, 16B-chunk XOR swizzle (chunk c of row r at c^(r&15)) ->
// fragment ds_read_b128 conflict-free (16 lanes hit 16 distinct chunks).
// A-tile staged via register prefetch issued after the compute barrier so
// the vmcnt drain overlaps MFMA+softmax of the current tile.
// Per-lane online softmax; 16-lane merge at end. grid = 32 mb x 16 jsp.
__global__ __launch_bounds__(256, 2) void main_kernel(
    const unsigned short* __restrict__ Wbf, const unsigned short* __restrict__ Abf,
    float* __restrict__ mP, float* __restrict__ zP, float* __restrict__ sP,
    int Jsplit, int JSWEEP, int nP) {
    __shared__ __align__(16) unsigned short sW[128 * 128];  // 32 KB
    __shared__ __align__(16) unsigned short sA[64 * 128];   // 16 KB

    const int mb = blockIdx.x / Jsplit;
    const int jsp = blockIdx.x % Jsplit;
    const int rowBase = mb * 128;
    const int t = threadIdx.x;
    const int wave = t >> 6, lane = t & 63, quad = lane >> 4, l16 = lane & 15;
    const int waveM = wave >> 1, waveN = wave & 1;

    // stage W tile (128 rows x 128 bf16), swizzled, once
    {
        int row = t >> 1, half = t & 1, rsw = row & 15;
        const unsigned short* src = Wbf + (size_t)(rowBase + row) * DIM + half * 64;
        unsigned short* dstrow = sW + row * 128;
#pragma unroll
        for (int i = 0; i < 8; i++) {
            int c = half * 8 + i;
            *(short8*)(dstrow + ((c ^ rsw) << 3)) = *(const short8*)(src + i * 8);
        }
    }

    float run_m[4][4], run_Z[4][4], run_s[4][4];
#pragma unroll
    for (int a = 0; a < 4; a++)
#pragma unroll
        for (int r = 0; r < 4; r++) {
            run_m[a][r] = -3.4e38f; run_Z[a][r] = 0.f; run_s[a][r] = 0.f;
        }

    // A-tile staging descriptors (thread -> row, quarter)
    const int arow = t >> 2, aq = t & 3, arsw = arow & 15;
    const unsigned short* asrc0 =
        Abf + (size_t)(jsp * JSWEEP * 64 + arow) * DIM + aq * 32;
    unsigned short* adst = sA + arow * 128;

    short8 pre[4];
#pragma unroll
    for (int i = 0; i < 4; i++) pre[i] = *(const short8*)(asrc0 + i * 8);

    const unsigned short* myW = sW + (size_t)(waveM * 64 + l16) * 128;
    const unsigned short* myA = sA + (size_t)(waveN * 32 + l16) * 128;

    for (int js = 0; js < JSWEEP; ++js) {
        __syncthreads();  // sA free to overwrite (prefetched loads long done)
#pragma unroll
        for (int i = 0; i < 4; i++) {
            int c = aq * 4 + i;
            *(short8*)(adst + ((c ^ arsw) << 3)) = pre[i];
        }
        __syncthreads();  // sA (and sW on first iter) ready

        if (js + 1 < JSWEEP) {  // issue next tile's loads; drain hides in compute
            const unsigned short* nsrc = asrc0 + (size_t)(js + 1) * 64 * DIM;
#pragma unroll
            for (int i = 0; i < 4; i++) pre[i] = *(const short8*)(nsrc + i * 8);
        }

        floatx4 acc[4][2];
#pragma unroll
        for (int mt = 0; mt < 4; mt++)
#pragma unroll
            for (int nt = 0; nt < 2; nt++) acc[mt][nt] = (floatx4)0.f;

#pragma unroll
        for (int kst = 0; kst < 4; ++kst) {
            const int coff = (((kst << 2) | quad) ^ l16) << 3;
            short8 bfrag[2];
#pragma unroll
            for (int nt = 0; nt < 2; nt++)
                bfrag[nt] = *(const short8*)(myA + nt * 16 * 128 + coff);
#pragma unroll
            for (int mt = 0; mt < 4; mt++) {
                short8 afrag = *(const short8*)(myW + mt * 16 * 128 + coff);
#pragma unroll
                for (int nt = 0; nt < 2; nt++)
                    acc[mt][nt] = __builtin_amdgcn_mfma_f32_16x16x32_bf16(
                        afrag, bfrag[nt], acc[mt][nt], 0, 0, 0);
            }
        }

        // per-lane online softmax update (lane's 2 columns only; no shfl)
#pragma unroll
        for (int mt = 0; mt < 4; mt++)
#pragma unroll
            for (int r = 0; r < 4; r++) {
                float v0 = acc[mt][0][r], v1 = acc[mt][1][r];
                float tm = fmaxf(v0, v1);
                float nm = fmaxf(run_m[mt][r], tm);
                run_Z[mt][r] = run_Z[mt][r] * __expf(run_m[mt][r] - nm)
                             + __expf(v0 - nm) + __expf(v1 - nm);
                run_m[mt][r] = nm;
                run_s[mt][r] += v0 + v1;
            }
    }

    // merge across the 16 lanes sharing each row, then write partials
    const int chunk = jsp * 2 + waveN;
#pragma unroll
    for (int mt = 0; mt < 4; mt++)
#pragma unroll
        for (int r = 0; r < 4; r++) {
            float m = run_m[mt][r], Z = run_Z[mt][r], s = run_s[mt][r];
#pragma unroll
            for (int mask = 1; mask < 16; mask <<= 1) {
                float om = __shfl_xor(m, mask);
                float oZ = __shfl_xor(Z, mask);
                float os = __shfl_xor(s, mask);
                float nm = fmaxf(m, om);
                Z = Z * __expf(m - nm) + oZ * __expf(om - nm);
                m = nm;
                s += os;
            }
            if (l16 == r) {
                int row = rowBase + waveM * 64 + mt * 16 + quad * 4 + r;
                size_t idx = (size_t)row * nP + chunk;
                mP[idx] = m; zP[idx] = Z; sP[idx] = s;
            }
        }
}

// 4 waves per block, one row k per wave: merge nP partial (m,Z,s) triples,
// write S_k (double).
__global__ __launch_bounds__(256) void combine_kernel(
    const float* __restrict__ mP, const float* __restrict__ zP,
    const float* __restrict__ sP, double* __restrict__ Sk, int B, int nP) {
    int k = blockIdx.x * 4 + (threadIdx.x >> 6);
    int l = threadIdx.x & 63;
    float m = -3.4e38f, Z = 0.0f, s = 0.0f;
    if (l < nP) {
        size_t idx = (size_t)k * nP + l;
        m = mP[idx]; Z = zP[idx]; s = sP[idx];
    }
    float M = m;
#pragma unroll
    for (int o = 32; o > 0; o >>= 1) M = fmaxf(M, __shfl_xor(M, o));
    float zt = Z * __expf(m - M);
    float st = s;
#pragma unroll
    for (int o = 32; o > 0; o >>= 1) {
        zt += __shfl_xor(zt, o);
        st += __shfl_xor(st, o);
    }
    if (l == 0) {
        Sk[k] = (double)st - (double)B * (double)M
                - (double)B * log((double)zt + 1e-12);
    }
}

// One block: loss = -(1/B^2) sum_k S_k * w_{l_k}. Histogram comes
// precomputed from bucket_kernel (meta[1..NBIN]) -- identical ints.
__global__ __launch_bounds__(1024) void final_kernel(
    const double* __restrict__ Sk, const int* __restrict__ labels,
    const int* __restrict__ cntG, float* __restrict__ out, int B) {
    __shared__ int hist[NBIN];
    __shared__ double sh[1024];
    int t = threadIdx.x;
    if (t < NBIN) hist[t] = cntG[t];
    __syncthreads();
    double acc = 0.0;
    for (int i = t; i < B; i += 1024) {
        double cnt = (double)hist[labels[i]];
        acc += Sk[i] * (cnt / (cnt + 1e-12));
    }
    sh[t] = acc;
    __syncthreads();
    for (int o = 512; o > 0; o >>= 1) {
        if (t < o) sh[t] += sh[t + o];
        __syncthreads();
    }
    if (t == 0) out[0] = (float)(-sh[0] / ((double)B * (double)B));
}

extern "C" void kernel_launch(void* const* d_in, const int* in_sizes, int n_in,
                              void* d_out, int out_size, void* d_ws, size_t ws_size,
                              hipStream_t stream) {
    const float* A = (const float*)d_in[0];
    const int* labels = (const int*)d_in[1];
    const float* Cov = (const float*)d_in[2];
    float* out = (float*)d_out;

    int B = in_sizes[0] / DIM;            // 4096
    int Jsplit = 16;
    int JSWEEP = B / (Jsplit * 64);       // 4
    int nP = Jsplit * 2;                  // 32 partials per row

    char* ws = (char*)d_ws;
    unsigned short* Wbf = (unsigned short*)ws;                       // B*128 bf16
    unsigned short* Abf = Wbf + (size_t)B * DIM;                     // B*128 bf16
    float* mP = (float*)(Abf + (size_t)B * DIM);                     // B*nP f32
    float* zP = mP + (size_t)B * nP;
    float* sP = zP + (size_t)B * nP;
    double* Sk = (double*)(sP + (size_t)B * nP);                     // B doubles
    int* perm = (int*)(Sk + B);                                      // B ints
    int* ckCls = perm + B;                                           // MAXCHUNK
    int* ckBase = ckCls + MAXCHUNK;
    int* ckNv = ckBase + MAXCHUNK;
    int* meta = ckNv + MAXCHUNK;                                     // 1 + NBIN

    bucket_kernel<<<1, 1024, 0, stream>>>(labels, B, perm, ckCls, ckBase,
                                          ckNv, meta);
    prep_kernel<<<MAXCHUNK, 256, 0, stream>>>(A, Cov, Wbf, Abf, perm, ckCls,
                                              ckBase, ckNv, meta);
    main_kernel<<<(B / 128) * Jsplit, 256, 0, stream>>>(Wbf, Abf, mP, zP, sP,
                                                        Jsplit, JSWEEP, nP);
    combine_kernel<<<B / 4, 256, 0, stream>>>(mP, zP, sP, Sk, B, nP);
    final_kernel<<<1, 1024, 0, stream>>>(Sk, labels, meta + 1, out, B);
}

// Round 4
// 101.138 us; speedup vs baseline: 1.0161x; 1.0161x over previous
//
#include <hip/hip_runtime.h>
#include <hip/hip_bf16.h>

// ContrastiveLoss: B=4096 rows, D=128 feature dim, C=100 classes.
// loss = -(1/B^2) * sum_k S_k * w_{l_k},  w_c = count_c/(count_c+1e-12)
//   S_k  = sum_j logits[k,j] - B*m_k - B*log(Z_k + 1e-12)
//   logits[k,j] = w_k . a_j,  w_k = (a_k + (a_k @ Cov[l_k]) / (2 T^2)) / T
// 4 dispatches: prep (bf16 conv + W build), main (MFMA flash logits,
// XOR-swizzled LDS + A-tile register prefetch), combine (S_k per row,
// no atomics, 4 rows/block), final (1-block label histogram + weighted sum).
// LESSONS (final state of the session):
// (R4) heavy fp64 tails fused into the MFMA kernel wreck regalloc (spills).
// (R7) single-address global tickets at 4096-block scale serialize ~145us.
// (R8/R1) bucket+chunked prep with a SERIAL t==0 chunk loop: +25us (whole
// GPU idle behind ~770 dependent stores + 2 extra dispatches + occupancy
// collapse).
// (R2) combine coarsening 4096->1024 blocks: neutral. Dispatch/block
// overhead is NOT the bottleneck.
// (R3) chunked prep retried with a FULLY PARALLEL bucket (LDS histogram +
// wave-0 shuffle scans + parallel chunk emission): still +1.5us. Root
// cause of the dead model: prep's 268MB redundant Cov reads are L2-hits
// latency-hidden behind the FMA chain at ~8 blocks/CU -- they were never
// serialized time. Capturable saving (~2-3us) < fixed cost of an extra
// dispatch + bucket (~3-4us). L2-side "redundant traffic" at high
// occupancy is mostly free; only HBM-side traffic or serialized stalls
// justify extra dispatches. DO NOT retry class-grouped prep.
// Budget: ~19us kernels + ~82us harness poison fills (2 x 256MiB @ ~41us,
// the only top-5 rocprof dispatches -- untouchable floor).

#define DIM 128
#define TEMP 0.07f

typedef __attribute__((ext_vector_type(8))) short short8;
typedef __attribute__((ext_vector_type(4))) float floatx4;

static __device__ __forceinline__ unsigned short f2bf(float f) {
    __hip_bfloat16 h = __float2bfloat16(f);
    union { __hip_bfloat16 h; unsigned short u; } c;
    c.h = h;
    return c.u;
}

// 2 rows per block (256 threads). Writes Abf (bf16 copy of A) and
// Wbf = bf16((a + (a @ Cov[l]) / (2T^2)) / T).
__global__ __launch_bounds__(256) void prep_kernel(
    const float* __restrict__ A, const int* __restrict__ labels,
    const float* __restrict__ Cov, unsigned short* __restrict__ Wbf,
    unsigned short* __restrict__ Abf) {
    const float inv2t2 = 1.0f / (2.0f * TEMP * TEMP);
    const float invt = 1.0f / TEMP;
    const int sub = threadIdx.x >> 7;   // which of 2 rows
    const int e = threadIdx.x & 127;
    const int i = blockIdx.x * 2 + sub;
    __shared__ float a[2][DIM];
    float av = A[(size_t)i * DIM + e];
    a[sub][e] = av;
    Abf[(size_t)i * DIM + e] = f2bf(av);
    __syncthreads();
    int c = labels[i];
    const float* Cp = Cov + (size_t)c * (DIM * DIM) + e;
    float acc = 0.0f;
#pragma unroll 8
    for (int d = 0; d < DIM; ++d) {
        acc = fmaf(a[sub][d], Cp[(size_t)d * DIM], acc);
    }
    Wbf[(size_t)i * DIM + e] = f2bf((av + acc * inv2t2) * invt);
}

// Block = 4 waves (2M x 2N). Block tile: 128 k-rows x 64 j-cols, K=128
// unrolled. Wave tile: 64x32 via 4(m) x 2(n) mfma_f32_16x16x32_bf16.
// LDS: PITCH=128, 16B-chunk XOR swizzle (chunk c of row r at c^(r&15)) ->
// fragment ds_read_b128 conflict-free (16 lanes hit 16 distinct chunks).
// A-tile staged via register prefetch issued after the compute barrier so
// the vmcnt drain overlaps MFMA+softmax of the current tile.
// Per-lane online softmax; 16-lane merge at end. grid = 32 mb x 16 jsp.
__global__ __launch_bounds__(256, 2) void main_kernel(
    const unsigned short* __restrict__ Wbf, const unsigned short* __restrict__ Abf,
    float* __restrict__ mP, float* __restrict__ zP, float* __restrict__ sP,
    int Jsplit, int JSWEEP, int nP) {
    __shared__ __align__(16) unsigned short sW[128 * 128];  // 32 KB
    __shared__ __align__(16) unsigned short sA[64 * 128];   // 16 KB

    const int mb = blockIdx.x / Jsplit;
    const int jsp = blockIdx.x % Jsplit;
    const int rowBase = mb * 128;
    const int t = threadIdx.x;
    const int wave = t >> 6, lane = t & 63, quad = lane >> 4, l16 = lane & 15;
    const int waveM = wave >> 1, waveN = wave & 1;

    // stage W tile (128 rows x 128 bf16), swizzled, once
    {
        int row = t >> 1, half = t & 1, rsw = row & 15;
        const unsigned short* src = Wbf + (size_t)(rowBase + row) * DIM + half * 64;
        unsigned short* dstrow = sW + row * 128;
#pragma unroll
        for (int i = 0; i < 8; i++) {
            int c = half * 8 + i;
            *(short8*)(dstrow + ((c ^ rsw) << 3)) = *(const short8*)(src + i * 8);
        }
    }

    float run_m[4][4], run_Z[4][4], run_s[4][4];
#pragma unroll
    for (int a = 0; a < 4; a++)
#pragma unroll
        for (int r = 0; r < 4; r++) {
            run_m[a][r] = -3.4e38f; run_Z[a][r] = 0.f; run_s[a][r] = 0.f;
        }

    // A-tile staging descriptors (thread -> row, quarter)
    const int arow = t >> 2, aq = t & 3, arsw = arow & 15;
    const unsigned short* asrc0 =
        Abf + (size_t)(jsp * JSWEEP * 64 + arow) * DIM + aq * 32;
    unsigned short* adst = sA + arow * 128;

    short8 pre[4];
#pragma unroll
    for (int i = 0; i < 4; i++) pre[i] = *(const short8*)(asrc0 + i * 8);

    const unsigned short* myW = sW + (size_t)(waveM * 64 + l16) * 128;
    const unsigned short* myA = sA + (size_t)(waveN * 32 + l16) * 128;

    for (int js = 0; js < JSWEEP; ++js) {
        __syncthreads();  // sA free to overwrite (prefetched loads long done)
#pragma unroll
        for (int i = 0; i < 4; i++) {
            int c = aq * 4 + i;
            *(short8*)(adst + ((c ^ arsw) << 3)) = pre[i];
        }
        __syncthreads();  // sA (and sW on first iter) ready

        if (js + 1 < JSWEEP) {  // issue next tile's loads; drain hides in compute
            const unsigned short* nsrc = asrc0 + (size_t)(js + 1) * 64 * DIM;
#pragma unroll
            for (int i = 0; i < 4; i++) pre[i] = *(const short8*)(nsrc + i * 8);
        }

        floatx4 acc[4][2];
#pragma unroll
        for (int mt = 0; mt < 4; mt++)
#pragma unroll
            for (int nt = 0; nt < 2; nt++) acc[mt][nt] = (floatx4)0.f;

#pragma unroll
        for (int kst = 0; kst < 4; ++kst) {
            const int coff = (((kst << 2) | quad) ^ l16) << 3;
            short8 bfrag[2];
#pragma unroll
            for (int nt = 0; nt < 2; nt++)
                bfrag[nt] = *(const short8*)(myA + nt * 16 * 128 + coff);
#pragma unroll
            for (int mt = 0; mt < 4; mt++) {
                short8 afrag = *(const short8*)(myW + mt * 16 * 128 + coff);
#pragma unroll
                for (int nt = 0; nt < 2; nt++)
                    acc[mt][nt] = __builtin_amdgcn_mfma_f32_16x16x32_bf16(
                        afrag, bfrag[nt], acc[mt][nt], 0, 0, 0);
            }
        }

        // per-lane online softmax update (lane's 2 columns only; no shfl)
#pragma unroll
        for (int mt = 0; mt < 4; mt++)
#pragma unroll
            for (int r = 0; r < 4; r++) {
                float v0 = acc[mt][0][r], v1 = acc[mt][1][r];
                float tm = fmaxf(v0, v1);
                float nm = fmaxf(run_m[mt][r], tm);
                run_Z[mt][r] = run_Z[mt][r] * __expf(run_m[mt][r] - nm)
                             + __expf(v0 - nm) + __expf(v1 - nm);
                run_m[mt][r] = nm;
                run_s[mt][r] += v0 + v1;
            }
    }

    // merge across the 16 lanes sharing each row, then write partials
    const int chunk = jsp * 2 + waveN;
#pragma unroll
    for (int mt = 0; mt < 4; mt++)
#pragma unroll
        for (int r = 0; r < 4; r++) {
            float m = run_m[mt][r], Z = run_Z[mt][r], s = run_s[mt][r];
#pragma unroll
            for (int mask = 1; mask < 16; mask <<= 1) {
                float om = __shfl_xor(m, mask);
                float oZ = __shfl_xor(Z, mask);
                float os = __shfl_xor(s, mask);
                float nm = fmaxf(m, om);
                Z = Z * __expf(m - nm) + oZ * __expf(om - nm);
                m = nm;
                s += os;
            }
            if (l16 == r) {
                int row = rowBase + waveM * 64 + mt * 16 + quad * 4 + r;
                size_t idx = (size_t)row * nP + chunk;
                mP[idx] = m; zP[idx] = Z; sP[idx] = s;
            }
        }
}

// 4 waves per block, one row k per wave: merge nP partial (m,Z,s) triples,
// write S_k (double).
__global__ __launch_bounds__(256) void combine_kernel(
    const float* __restrict__ mP, const float* __restrict__ zP,
    const float* __restrict__ sP, double* __restrict__ Sk, int B, int nP) {
    int k = blockIdx.x * 4 + (threadIdx.x >> 6);
    int l = threadIdx.x & 63;
    float m = -3.4e38f, Z = 0.0f, s = 0.0f;
    if (l < nP) {
        size_t idx = (size_t)k * nP + l;
        m = mP[idx]; Z = zP[idx]; s = sP[idx];
    }
    float M = m;
#pragma unroll
    for (int o = 32; o > 0; o >>= 1) M = fmaxf(M, __shfl_xor(M, o));
    float zt = Z * __expf(m - M);
    float st = s;
#pragma unroll
    for (int o = 32; o > 0; o >>= 1) {
        zt += __shfl_xor(zt, o);
        st += __shfl_xor(st, o);
    }
    if (l == 0) {
        Sk[k] = (double)st - (double)B * (double)M
                - (double)B * log((double)zt + 1e-12);
    }
}

// One block: histogram labels in LDS, then loss = -(1/B^2) sum_k S_k * w_{l_k}.
__global__ __launch_bounds__(1024) void final_kernel(
    const double* __restrict__ Sk, const int* __restrict__ labels,
    float* __restrict__ out, int B) {
    __shared__ int hist[128];
    __shared__ double sh[1024];
    int t = threadIdx.x;
    if (t < 128) hist[t] = 0;
    __syncthreads();
    for (int i = t; i < B; i += 1024) atomicAdd(&hist[labels[i]], 1);
    __syncthreads();
    double acc = 0.0;
    for (int i = t; i < B; i += 1024) {
        double cnt = (double)hist[labels[i]];
        acc += Sk[i] * (cnt / (cnt + 1e-12));
    }
    sh[t] = acc;
    __syncthreads();
    for (int o = 512; o > 0; o >>= 1) {
        if (t < o) sh[t] += sh[t + o];
        __syncthreads();
    }
    if (t == 0) out[0] = (float)(-sh[0] / ((double)B * (double)B));
}

extern "C" void kernel_launch(void* const* d_in, const int* in_sizes, int n_in,
                              void* d_out, int out_size, void* d_ws, size_t ws_size,
                              hipStream_t stream) {
    const float* A = (const float*)d_in[0];
    const int* labels = (const int*)d_in[1];
    const float* Cov = (const float*)d_in[2];
    float* out = (float*)d_out;

    int B = in_sizes[0] / DIM;            // 4096
    int Jsplit = 16;
    int JSWEEP = B / (Jsplit * 64);       // 4
    int nP = Jsplit * 2;                  // 32 partials per row

    char* ws = (char*)d_ws;
    unsigned short* Wbf = (unsigned short*)ws;                       // B*128 bf16
    unsigned short* Abf = Wbf + (size_t)B * DIM;                     // B*128 bf16
    float* mP = (float*)(Abf + (size_t)B * DIM);                     // B*nP f32
    float* zP = mP + (size_t)B * nP;
    float* sP = zP + (size_t)B * nP;
    double* Sk = (double*)(sP + (size_t)B * nP);                     // B doubles

    prep_kernel<<<B / 2, 256, 0, stream>>>(A, labels, Cov, Wbf, Abf);
    main_kernel<<<(B / 128) * Jsplit, 256, 0, stream>>>(Wbf, Abf, mP, zP, sP,
                                                        Jsplit, JSWEEP, nP);
    combine_kernel<<<B / 4, 256, 0, stream>>>(mP, zP, sP, Sk, B, nP);
    final_kernel<<<1, 1024, 0, stream>>>(Sk, labels, out, B);
}